// Round 13
// baseline (273.592 us; speedup 1.0000x reference)
//
#include <hip/hip_runtime.h>
#include <cstdint>
#include <cstddef>

#define DD   512
#define NTOK 32768
#define NE   8
#define BM   128
#define BN   128
#define BK   64
#define NT   (DD / BK)   // 8 k-steps
#define RBLK 1024

typedef unsigned int  u32;
typedef unsigned short u16;
typedef unsigned long long u64;
using f16x8  = __attribute__((ext_vector_type(8))) _Float16;
using f32x16 = __attribute__((ext_vector_type(16))) float;

// LDS (u16 units): single buffer {A, B}, each 128x64 f16 (16KB) -> 32KB
#define OA 0
#define OB 8192

__device__ __forceinline__ u16 f16bits(float f) {
    union { _Float16 h; u16 u; } p;
    p.h = (_Float16)f;
    return p.u;
}
__device__ __forceinline__ float h2f(u16 v) {
    union { _Float16 h; u16 u; } p;
    p.u = v;
    return (float)p.h;
}
__device__ __forceinline__ uint4 pack_f16x8(const float4& a, const float4& b) {
    uint4 r;
    r.x = (u32)f16bits(a.x) | ((u32)f16bits(a.y) << 16);
    r.y = (u32)f16bits(a.z) | ((u32)f16bits(a.w) << 16);
    r.z = (u32)f16bits(b.x) | ((u32)f16bits(b.y) << 16);
    r.w = (u32)f16bits(b.z) | ((u32)f16bits(b.w) << 16);
    return r;
}

__device__ __forceinline__ void gl16(const void* src, const u16* ldsdst) {
    __builtin_amdgcn_global_load_lds(
        (const __attribute__((address_space(1))) u32*)src,
        (__attribute__((address_space(3))) u32*)(void*)ldsdst, 16, 0, 0);
}

// ---------------- routing: block-aggregated counts ----------------
__global__ __launch_bounds__(RBLK) void route_kernel(
    const float* __restrict__ x,
    const float* __restrict__ Wg,
    const float* __restrict__ bg,
    int t0, int T,
    int* __restrict__ counts,
    int* __restrict__ eids,
    float* __restrict__ wts) {
    __shared__ int lcnt[NE];
    int tid = threadIdx.x;
    if (tid < NE) lcnt[tid] = 0;
    __syncthreads();

    int i = blockIdx.x * RBLK + tid;
    bool active = (i < T);
    int e0 = 0, e1 = 0;
    if (active) {
        int n = t0 + i;
        const float* xr = x + (size_t)n * DD + (DD - 3);
        float x0 = xr[0], x1 = xr[1], x2 = xr[2];
        float g[NE];
#pragma unroll
        for (int e = 0; e < NE; e++)
            g[e] = x0 * Wg[e] + x1 * Wg[NE + e] + x2 * Wg[2 * NE + e] + bg[e];
        float v0 = g[0];
#pragma unroll
        for (int e = 1; e < NE; e++) if (g[e] > v0) { v0 = g[e]; e0 = e; }
        float v1 = -3.0e38f; e1 = -1;
#pragma unroll
        for (int e = 0; e < NE; e++) if (e != e0 && g[e] > v1) { v1 = g[e]; e1 = e; }
        float t = expf(v1 - v0);
        float s = 1.0f / (1.0f + t);
        eids[2 * i] = e0; eids[2 * i + 1] = e1;
        wts[2 * i] = s;  wts[2 * i + 1] = t * s;
    }

    int lane = tid & 63;
#pragma unroll
    for (int k = 0; k < 2; k++) {
        int e = active ? (k ? e1 : e0) : -1;
#pragma unroll
        for (int ex = 0; ex < NE; ex++) {
            u64 m = __ballot(e == ex);
            if (m && lane == 0) atomicAdd(&lcnt[ex], __popcll(m));
        }
    }
    __syncthreads();
    if (tid < NE && lcnt[tid]) atomicAdd(&counts[tid], lcnt[tid]);
}

// ---------------- padded prefix sum (pad to BM) ----------------
__global__ void offsets_kernel(const int* __restrict__ counts,
                               int* __restrict__ off,
                               int* __restrict__ cursor) {
    if (threadIdx.x == 0) {
        int acc = 0;
        for (int e = 0; e < NE; e++) {
            off[e] = acc;
            cursor[e] = acc;
            acc += (counts[e] + (BM - 1)) & ~(BM - 1);
        }
        off[NE] = acc;
    }
}

// ---------------- scatter: block/wave-aggregated ----------------
__global__ __launch_bounds__(RBLK) void scatter_kernel(
    int t0, int T,
    const int* __restrict__ eids,
    int* __restrict__ cursor,
    int* __restrict__ list_token,
    int* __restrict__ posl) {
    __shared__ int lcnt[NE], lbase[NE];
    __shared__ int woff[RBLK / 64][NE];
    int tid = threadIdx.x, lane = tid & 63, wv = tid >> 6;
    int i = blockIdx.x * RBLK + tid;
    bool active = (i < T);
    u64 lmask = (1ull << lane) - 1ull;

#pragma unroll
    for (int k = 0; k < 2; k++) {
        if (tid < NE) lcnt[tid] = 0;
        __syncthreads();
        int e = active ? eids[2 * i + k] : -1;
        u64 mymask = 0;
#pragma unroll
        for (int ex = 0; ex < NE; ex++) {
            u64 m = __ballot(e == ex);
            if (e == ex) mymask = m;
            if (m && lane == 0) woff[wv][ex] = atomicAdd(&lcnt[ex], __popcll(m));
        }
        __syncthreads();
        if (tid < NE) lbase[tid] = lcnt[tid] ? atomicAdd(&cursor[tid], lcnt[tid]) : 0;
        __syncthreads();
        if (active) {
            int p = lbase[e] + woff[wv][e] + __popcll(mymask & lmask);
            list_token[p] = t0 + i;
            posl[2 * i + k] = p;
        }
        __syncthreads();
    }
}

// ---------------- weight transpose + fp16 convert ----------------
// Wh[e][l][k][n] (l<3) / Wo[e][k][n]  ->  Wt[(e*4+l)][n][k] fp16
__global__ void convert_w(const float* __restrict__ Wh,
                          const float* __restrict__ Wo,
                          u16* __restrict__ Wt) {
    __shared__ float tile[32][33];
    int z = blockIdx.z;             // e*4 + l
    int e = z >> 2, l = z & 3;
    const float* src = (l < 3) ? (Wh + ((size_t)e * 3 + l) * DD * DD)
                               : (Wo + (size_t)e * DD * DD);
    int bx = blockIdx.x, by = blockIdx.y;
    int tx = threadIdx.x, ty = threadIdx.y; // 32 x 8
#pragma unroll
    for (int j = 0; j < 4; j++)
        tile[ty + j * 8][tx] = src[(size_t)(by * 32 + ty + j * 8) * DD + bx * 32 + tx];
    __syncthreads();
    u16* d = Wt + (size_t)z * DD * DD;
#pragma unroll
    for (int j = 0; j < 4; j++) {
        int n = bx * 32 + ty + j * 8;
        int k = by * 32 + tx;
        d[(size_t)n * DD + k] = f16bits(tile[tx][ty + j * 8]);
    }
}

// ---------------- fp16 MFMA GEMM: 128x128x64-step, 4 waves, wave-tile 64x64 ----------------
// MFMA 32x32x16: wave-tile = 2x2 frags of 32x32; per k-step 4 k-subs of 16.
template <bool GATHER, bool RELU>
__global__ __launch_bounds__(256, 4) void moe_gemm(
    const float* __restrict__ Xf,
    const u16* __restrict__ Ain,          // fp16 activations (when !GATHER)
    const int* __restrict__ list_token,
    const u16* __restrict__ Wt,
    int layer,
    const float* __restrict__ bptr, int bestride,
    const int* __restrict__ off,
    u16* __restrict__ Ch)                 // fp16 output
{
    // XCD-bijective swizzle (grid multiple of 8); cb-minor within XCD chunk
    u32 nb = gridDim.x, qq = nb >> 3, bid = blockIdx.x;
    u32 wg = (bid & 7) * qq + (bid >> 3);
    int rb = (int)(wg >> 2) * BM;
    if (rb >= off[NE]) return;
    int cb = (int)(wg & 3) * BN;
    int e = 0;
#pragma unroll
    for (int s = 1; s < NE; s++) if (rb >= off[s]) e = s;

    __shared__ u16 lds[16384];   // 32 KiB

    const int tid = threadIdx.x;
    const int lane = tid & 63, wv = tid >> 6;

    // staging: per array 1024 chunks (128 rows x 8 units of 16B); 4 chunks/thread
    // chunk c = j*256 + tid; row = c>>3, phys unit = c&7,
    // logical (source) unit us = (c&7) ^ (row&7)
    int rowj[4], usj[4];
#pragma unroll
    for (int j = 0; j < 4; j++) {
        int c = j * 256 + tid;
        rowj[j] = c >> 3;
        usj[j]  = (c & 7) ^ (rowj[j] & 7);
    }

    const size_t wbase = ((size_t)e * 4 + layer) * (size_t)DD * DD;
    const u16* bS[4];
    const u16* aS[4];
    const float* aF[4];
    int tokj[4];
#pragma unroll
    for (int j = 0; j < 4; j++) {
        bS[j] = Wt + wbase + (size_t)(cb + rowj[j]) * DD + usj[j] * 8;
        if (GATHER) {
            tokj[j] = list_token[rb + rowj[j]];
            aF[j] = Xf + (size_t)(tokj[j] < 0 ? 0 : tokj[j]) * DD + usj[j] * 8;
        } else {
            aS[j] = Ain + (size_t)(rb + rowj[j]) * DD + usj[j] * 8;
        }
    }
    // wave-uniform LDS chunk bases (u16 idx): chunk (j*256 + wv*64), lane auto x16B
    const int cb8[4] = { wv * 512, 2048 + wv * 512, 4096 + wv * 512, 6144 + wv * 512 };

    // MFMA read mapping: 2x2 wave grid, wave-tile 64x64 of 2x2 32x32 frags.
    // Frag read: row = wtile + mi*32 + (lane&31); k-unit = ksub*2 + (lane>>5)
    const int l31 = lane & 31, lh = lane >> 5;
    const int wr = (wv >> 1) * 64, wc = (wv & 1) * 64;
    u32 aoffk[4][2], boffk[4][2];
#pragma unroll
    for (int ks = 0; ks < 4; ks++)
#pragma unroll
        for (int i = 0; i < 2; i++) {
            int ar = wr + i * 32 + l31;
            aoffk[ks][i] = (u32)(ar * 64 + ((((ks << 1) + lh) ^ (ar & 7)) << 3));
            int br = wc + i * 32 + l31;
            boffk[ks][i] = (u32)(br * 64 + ((((ks << 1) + lh) ^ (br & 7)) << 3));
        }

    f32x16 acc[2][2];
#pragma unroll
    for (int i = 0; i < 2; i++)
#pragma unroll
        for (int j = 0; j < 2; j++)
            acc[i][j] = (f32x16){0.f,0.f,0.f,0.f,0.f,0.f,0.f,0.f,
                                 0.f,0.f,0.f,0.f,0.f,0.f,0.f,0.f};

    for (int t = 0; t < NT; t++) {
        const int k0 = t * BK;
        // ---- stage tile t (B via gl16; A via gl16 or gathered fp32->fp16) ----
#pragma unroll
        for (int j = 0; j < 4; j++)
            gl16(bS[j] + k0, &lds[OB + cb8[j]]);
        if (GATHER) {
#pragma unroll
            for (int j = 0; j < 4; j++) {
                const float4* fp = (const float4*)(aF[j] + k0);
                float4 f0 = fp[0], f1 = fp[1];
                if (tokj[j] < 0) { f0 = make_float4(0.f, 0.f, 0.f, 0.f); f1 = f0; }
                *(uint4*)&lds[OA + (j * 256 + tid) * 8] = pack_f16x8(f0, f1);
            }
        } else {
#pragma unroll
            for (int j = 0; j < 4; j++)
                gl16(aS[j] + k0, &lds[OA + cb8[j]]);
        }
        __syncthreads();

        // ---- compute: 16 ds_read_b128 + 16 MFMA(32x32x16) per wave ----
#pragma unroll
        for (int ks = 0; ks < 4; ks++) {
            f16x8 a[2], b[2];
#pragma unroll
            for (int i = 0; i < 2; i++) {
                a[i] = *(const f16x8*)&lds[OA + aoffk[ks][i]];
                b[i] = *(const f16x8*)&lds[OB + boffk[ks][i]];
            }
#pragma unroll
            for (int mi = 0; mi < 2; mi++)
#pragma unroll
                for (int ni = 0; ni < 2; ni++)
                    acc[mi][ni] = __builtin_amdgcn_mfma_f32_32x32x16_f16(
                        a[mi], b[ni], acc[mi][ni], 0, 0, 0);
        }
        __syncthreads();
    }

    // ---- epilogue: bias (+relu); fp16 store ----
    // C/D map: col = lane&31, row = (reg&3) + 8*(reg>>2) + 4*(lane>>5)
#pragma unroll
    for (int ni = 0; ni < 2; ni++) {
        int col = cb + wc + ni * 32 + l31;
        float bbias = bptr[e * bestride + col];
#pragma unroll
        for (int mi = 0; mi < 2; mi++) {
            int rbase = rb + wr + mi * 32 + 4 * lh;
#pragma unroll
            for (int r = 0; r < 16; r++) {
                int row = rbase + (r & 3) + 8 * (r >> 2);
                float v = acc[mi][ni][r] + bbias;
                if (RELU) v = fmaxf(v, 0.f);
                Ch[(size_t)row * DD + col] = f16bits(v);
            }
        }
    }
}

// ---------------- combine: out[n] = w0*y[p0] + w1*y[p1] (y fp16) ----------------
__global__ void combine_kernel(int t0, int T,
                               const u16* __restrict__ y,
                               const int* __restrict__ posl,
                               const float* __restrict__ wts,
                               float* __restrict__ out) {
    int idx = blockIdx.x * blockDim.x + threadIdx.x;
    if (idx >= T * (DD / 4)) return;
    int i = idx >> 7;
    int j = idx & 127;
    int p0 = posl[2 * i], p1 = posl[2 * i + 1];
    float w0 = wts[2 * i], w1 = wts[2 * i + 1];
    ushort4 a = ((const ushort4*)(y + (size_t)p0 * DD))[j];
    ushort4 b = ((const ushort4*)(y + (size_t)p1 * DD))[j];
    float4 c;
    c.x = w0 * h2f(a.x) + w1 * h2f(b.x);
    c.y = w0 * h2f(a.y) + w1 * h2f(b.y);
    c.z = w0 * h2f(a.z) + w1 * h2f(b.z);
    c.w = w0 * h2f(a.w) + w1 * h2f(b.w);
    ((float4*)(out + (size_t)(t0 + i) * DD))[j] = c;
}

extern "C" void kernel_launch(void* const* d_in, const int* in_sizes, int n_in,
                              void* d_out, int out_size, void* d_ws, size_t ws_size,
                              hipStream_t stream) {
    const float* x  = (const float*)d_in[0];
    const float* Wg = (const float*)d_in[1];
    const float* bg = (const float*)d_in[2];
    const float* Wh = (const float*)d_in[3];
    const float* bh = (const float*)d_in[4];
    const float* Wo = (const float*)d_in[5];
    const float* bo = (const float*)d_in[6];
    float* out = (float*)d_out;

    const size_t WT_ELEMS = (size_t)NE * 4 * DD * DD;   // 8.39M fp16
    int T = NTOK;
    while (T > 64) {
        size_t C = 2 * (size_t)T + NE * BM;
        size_t need = 4096 + WT_ELEMS * 2 + 3 * ((size_t)T * 2 * 4)
                    + C * 4 + 512
                    + 3 * (C * (size_t)DD * 2);   // bufA, bufB, bufY fp16
        if (need <= ws_size) break;
        T >>= 1;
    }
    int phases = (NTOK + T - 1) / T;
    size_t C = 2 * (size_t)T + NE * BM;

    char* p = (char*)d_ws;
    int* counts = (int*)p;
    int* off    = (int*)(p + 64);
    int* cursor = (int*)(p + 128);
    char* q = p + 4096;
    u16* Wt = (u16*)q;    q += WT_ELEMS * 2;
    int* eids = (int*)q;  q += (size_t)T * 2 * 4;
    int* posl = (int*)q;  q += (size_t)T * 2 * 4;
    float* wts = (float*)q; q += (size_t)T * 2 * 4;
    int* list_token = (int*)q; q += C * 4;
    q = (char*)(((uintptr_t)q + 255) & ~(uintptr_t)255);
    u16* bufA = (u16*)q;  q += C * DD * 2;
    u16* bufB = (u16*)q;  q += C * DD * 2;
    u16* bufY = (u16*)q;

    convert_w<<<dim3(16, 16, 32), dim3(32, 8), 0, stream>>>(Wh, Wo, Wt);

    for (int ph = 0; ph < phases; ph++) {
        int t0 = ph * T;
        int Tc = (NTOK - t0 < T) ? (NTOK - t0) : T;

        hipMemsetAsync(counts, 0, 256, stream);
        hipMemsetAsync(list_token, 0xFF, C * 4, stream);

        route_kernel<<<(Tc + RBLK - 1) / RBLK, RBLK, 0, stream>>>(
            x, Wg, bg, t0, Tc, counts, eids, wts);
        offsets_kernel<<<1, 64, 0, stream>>>(counts, off, cursor);
        scatter_kernel<<<(Tc + RBLK - 1) / RBLK, RBLK, 0, stream>>>(
            t0, Tc, eids, cursor, list_token, posl);

        // grid: (C/BM) row-panels x 4 col-blocks, 1-D, multiple of 8 for XCD swizzle
        unsigned NB = (unsigned)(C / BM) * (DD / BN);
        moe_gemm<true, true><<<NB, 256, 0, stream>>>(
            x, nullptr, list_token, Wt, 0,
            bh, 3 * DD, off, bufA);
        moe_gemm<false, true><<<NB, 256, 0, stream>>>(
            nullptr, bufA, nullptr, Wt, 1,
            bh + DD, 3 * DD, off, bufB);
        moe_gemm<false, true><<<NB, 256, 0, stream>>>(
            nullptr, bufB, nullptr, Wt, 2,
            bh + 2 * DD, 3 * DD, off, bufA);
        moe_gemm<false, false><<<NB, 256, 0, stream>>>(
            nullptr, bufA, nullptr, Wt, 3,
            bo, DD, off, bufY);

        combine_kernel<<<((size_t)Tc * (DD / 4) + 255) / 256, 256, 0, stream>>>(
            t0, Tc, bufY, posl, wts, out);
    }
}

// Round 14
// 263.053 us; speedup vs baseline: 1.0401x; 1.0401x over previous
//
#include <hip/hip_runtime.h>
#include <cstdint>
#include <cstddef>

#define DD   512
#define NTOK 32768
#define NE   8
#define BM   128
#define BN   128
#define BK   64
#define NT   (DD / BK)   // 8 k-steps
#define RBLK 1024

typedef unsigned int  u32;
typedef unsigned short u16;
typedef unsigned long long u64;
using f16x8 = __attribute__((ext_vector_type(8))) _Float16;
using f32x4 = __attribute__((ext_vector_type(4))) float;

// LDS (u16 units): single buffer {A, B}, each 128x64 f16 (16KB) -> 32KB
#define OA 0
#define OB 8192

__device__ __forceinline__ u16 f16bits(float f) {
    union { _Float16 h; u16 u; } p;
    p.h = (_Float16)f;
    return p.u;
}
__device__ __forceinline__ float h2f(u16 v) {
    union { _Float16 h; u16 u; } p;
    p.u = v;
    return (float)p.h;
}
__device__ __forceinline__ uint4 pack_f16x8(const float4& a, const float4& b) {
    uint4 r;
    r.x = (u32)f16bits(a.x) | ((u32)f16bits(a.y) << 16);
    r.y = (u32)f16bits(a.z) | ((u32)f16bits(a.w) << 16);
    r.z = (u32)f16bits(b.x) | ((u32)f16bits(b.y) << 16);
    r.w = (u32)f16bits(b.z) | ((u32)f16bits(b.w) << 16);
    return r;
}

__device__ __forceinline__ void gl16(const void* src, const u16* ldsdst) {
    __builtin_amdgcn_global_load_lds(
        (const __attribute__((address_space(1))) u32*)src,
        (__attribute__((address_space(3))) u32*)(void*)ldsdst, 16, 0, 0);
}

// ---------------- routing: block-aggregated counts ----------------
__global__ __launch_bounds__(RBLK) void route_kernel(
    const float* __restrict__ x,
    const float* __restrict__ Wg,
    const float* __restrict__ bg,
    int t0, int T,
    int* __restrict__ counts,
    int* __restrict__ eids,
    float* __restrict__ wts) {
    __shared__ int lcnt[NE];
    int tid = threadIdx.x;
    if (tid < NE) lcnt[tid] = 0;
    __syncthreads();

    int i = blockIdx.x * RBLK + tid;
    bool active = (i < T);
    int e0 = 0, e1 = 0;
    if (active) {
        int n = t0 + i;
        const float* xr = x + (size_t)n * DD + (DD - 3);
        float x0 = xr[0], x1 = xr[1], x2 = xr[2];
        float g[NE];
#pragma unroll
        for (int e = 0; e < NE; e++)
            g[e] = x0 * Wg[e] + x1 * Wg[NE + e] + x2 * Wg[2 * NE + e] + bg[e];
        float v0 = g[0];
#pragma unroll
        for (int e = 1; e < NE; e++) if (g[e] > v0) { v0 = g[e]; e0 = e; }
        float v1 = -3.0e38f; e1 = -1;
#pragma unroll
        for (int e = 0; e < NE; e++) if (e != e0 && g[e] > v1) { v1 = g[e]; e1 = e; }
        float t = expf(v1 - v0);
        float s = 1.0f / (1.0f + t);
        eids[2 * i] = e0; eids[2 * i + 1] = e1;
        wts[2 * i] = s;  wts[2 * i + 1] = t * s;
    }

    int lane = tid & 63;
#pragma unroll
    for (int k = 0; k < 2; k++) {
        int e = active ? (k ? e1 : e0) : -1;
#pragma unroll
        for (int ex = 0; ex < NE; ex++) {
            u64 m = __ballot(e == ex);
            if (m && lane == 0) atomicAdd(&lcnt[ex], __popcll(m));
        }
    }
    __syncthreads();
    if (tid < NE && lcnt[tid]) atomicAdd(&counts[tid], lcnt[tid]);
}

// ---------------- padded prefix sum (pad to BM) ----------------
__global__ void offsets_kernel(const int* __restrict__ counts,
                               int* __restrict__ off,
                               int* __restrict__ cursor) {
    if (threadIdx.x == 0) {
        int acc = 0;
        for (int e = 0; e < NE; e++) {
            off[e] = acc;
            cursor[e] = acc;
            acc += (counts[e] + (BM - 1)) & ~(BM - 1);
        }
        off[NE] = acc;
    }
}

// ---------------- scatter: block/wave-aggregated ----------------
__global__ __launch_bounds__(RBLK) void scatter_kernel(
    int t0, int T,
    const int* __restrict__ eids,
    int* __restrict__ cursor,
    int* __restrict__ list_token,
    int* __restrict__ posl) {
    __shared__ int lcnt[NE], lbase[NE];
    __shared__ int woff[RBLK / 64][NE];
    int tid = threadIdx.x, lane = tid & 63, wv = tid >> 6;
    int i = blockIdx.x * RBLK + tid;
    bool active = (i < T);
    u64 lmask = (1ull << lane) - 1ull;

#pragma unroll
    for (int k = 0; k < 2; k++) {
        if (tid < NE) lcnt[tid] = 0;
        __syncthreads();
        int e = active ? eids[2 * i + k] : -1;
        u64 mymask = 0;
#pragma unroll
        for (int ex = 0; ex < NE; ex++) {
            u64 m = __ballot(e == ex);
            if (e == ex) mymask = m;
            if (m && lane == 0) woff[wv][ex] = atomicAdd(&lcnt[ex], __popcll(m));
        }
        __syncthreads();
        if (tid < NE) lbase[tid] = lcnt[tid] ? atomicAdd(&cursor[tid], lcnt[tid]) : 0;
        __syncthreads();
        if (active) {
            int p = lbase[e] + woff[wv][e] + __popcll(mymask & lmask);
            list_token[p] = t0 + i;
            posl[2 * i + k] = p;
        }
        __syncthreads();
    }
}

// ---------------- weight transpose + fp16 convert ----------------
// Wh[e][l][k][n] (l<3) / Wo[e][k][n]  ->  Wt[(e*4+l)][n][k] fp16
__global__ void convert_w(const float* __restrict__ Wh,
                          const float* __restrict__ Wo,
                          u16* __restrict__ Wt) {
    __shared__ float tile[32][33];
    int z = blockIdx.z;             // e*4 + l
    int e = z >> 2, l = z & 3;
    const float* src = (l < 3) ? (Wh + ((size_t)e * 3 + l) * DD * DD)
                               : (Wo + (size_t)e * DD * DD);
    int bx = blockIdx.x, by = blockIdx.y;
    int tx = threadIdx.x, ty = threadIdx.y; // 32 x 8
#pragma unroll
    for (int j = 0; j < 4; j++)
        tile[ty + j * 8][tx] = src[(size_t)(by * 32 + ty + j * 8) * DD + bx * 32 + tx];
    __syncthreads();
    u16* d = Wt + (size_t)z * DD * DD;
#pragma unroll
    for (int j = 0; j < 4; j++) {
        int n = bx * 32 + ty + j * 8;
        int k = by * 32 + tx;
        d[(size_t)n * DD + k] = f16bits(tile[tx][ty + j * 8]);
    }
}

// ---------------- fp16 MFMA GEMM: 128x128x64-step, 4 waves, wave-tile 64x64 ----------------
template <bool GATHER, bool RELU>
__global__ __launch_bounds__(256, 3) void moe_gemm(
    const float* __restrict__ Xf,
    const u16* __restrict__ Ain,          // fp16 activations (when !GATHER)
    const int* __restrict__ list_token,
    const u16* __restrict__ Wt,
    int layer,
    const float* __restrict__ bptr, int bestride,
    const int* __restrict__ off,
    u16* __restrict__ Ch)                 // fp16 output
{
    // XCD-bijective swizzle (grid multiple of 8); cb-minor within XCD chunk
    u32 nb = gridDim.x, qq = nb >> 3, bid = blockIdx.x;
    u32 wg = (bid & 7) * qq + (bid >> 3);
    int rb = (int)(wg >> 2) * BM;
    if (rb >= off[NE]) return;
    int cb = (int)(wg & 3) * BN;
    int e = 0;
#pragma unroll
    for (int s = 1; s < NE; s++) if (rb >= off[s]) e = s;

    __shared__ u16 lds[16384];   // 32 KiB

    const int tid = threadIdx.x;
    const int lane = tid & 63, wv = tid >> 6;

    // staging: per array 1024 chunks (128 rows x 8 units of 16B); 4 chunks/thread
    // chunk c = j*256 + tid; row = c>>3, phys unit = c&7,
    // logical (source) unit us = (c&7) ^ (row&7)
    int rowj[4], usj[4];
#pragma unroll
    for (int j = 0; j < 4; j++) {
        int c = j * 256 + tid;
        rowj[j] = c >> 3;
        usj[j]  = (c & 7) ^ (rowj[j] & 7);
    }

    const size_t wbase = ((size_t)e * 4 + layer) * (size_t)DD * DD;
    const u16* bS[4];
    const u16* aS[4];
    const float* aF[4];
    int tokj[4];
#pragma unroll
    for (int j = 0; j < 4; j++) {
        bS[j] = Wt + wbase + (size_t)(cb + rowj[j]) * DD + usj[j] * 8;
        if (GATHER) {
            tokj[j] = list_token[rb + rowj[j]];
            aF[j] = Xf + (size_t)(tokj[j] < 0 ? 0 : tokj[j]) * DD + usj[j] * 8;
        } else {
            aS[j] = Ain + (size_t)(rb + rowj[j]) * DD + usj[j] * 8;
        }
    }
    // wave-uniform LDS chunk bases (u16 idx): chunk (j*256 + wv*64), lane auto x16B
    const int cb8[4] = { wv * 512, 2048 + wv * 512, 4096 + wv * 512, 6144 + wv * 512 };

    // MFMA read mapping: 2x2 wave grid, wave-tile 64x64; kh in {0,1} covers k 0-31/32-63
    const int r15 = lane & 15, lg = lane >> 4;
    const int wr = (wv >> 1) * 64, wc = (wv & 1) * 64;
    u32 aoffk[2][4], boffk[2][4];
#pragma unroll
    for (int kh = 0; kh < 2; kh++)
#pragma unroll
        for (int i = 0; i < 4; i++) {
            int ar = wr + i * 16 + r15;
            aoffk[kh][i] = (u32)(ar * 64 + (((lg + 4 * kh) ^ (ar & 7)) << 3));
            int br = wc + i * 16 + r15;
            boffk[kh][i] = (u32)(br * 64 + (((lg + 4 * kh) ^ (br & 7)) << 3));
        }

    f32x4 acc[4][4];
#pragma unroll
    for (int i = 0; i < 4; i++)
#pragma unroll
        for (int j = 0; j < 4; j++) acc[i][j] = (f32x4){0.f, 0.f, 0.f, 0.f};

    for (int t = 0; t < NT; t++) {
        const int k0 = t * BK;
        // ---- stage tile t (B via gl16; A via gl16 or gathered fp32->fp16) ----
#pragma unroll
        for (int j = 0; j < 4; j++)
            gl16(bS[j] + k0, &lds[OB + cb8[j]]);
        if (GATHER) {
#pragma unroll
            for (int j = 0; j < 4; j++) {
                const float4* fp = (const float4*)(aF[j] + k0);
                float4 f0 = fp[0], f1 = fp[1];
                if (tokj[j] < 0) { f0 = make_float4(0.f, 0.f, 0.f, 0.f); f1 = f0; }
                *(uint4*)&lds[OA + (j * 256 + tid) * 8] = pack_f16x8(f0, f1);
            }
        } else {
#pragma unroll
            for (int j = 0; j < 4; j++)
                gl16(aS[j] + k0, &lds[OA + cb8[j]]);
        }
        __syncthreads();

        // ---- compute: 16 ds_read_b128 + 32 MFMA per wave ----
#pragma unroll
        for (int kh = 0; kh < 2; kh++) {
            f16x8 a[4];
#pragma unroll
            for (int mi = 0; mi < 4; mi++)
                a[mi] = *(const f16x8*)&lds[OA + aoffk[kh][mi]];
#pragma unroll
            for (int ni = 0; ni < 4; ni++) {
                f16x8 b = *(const f16x8*)&lds[OB + boffk[kh][ni]];
#pragma unroll
                for (int mi = 0; mi < 4; mi++)
                    acc[mi][ni] = __builtin_amdgcn_mfma_f32_16x16x32_f16(a[mi], b, acc[mi][ni], 0, 0, 0);
            }
        }
        __syncthreads();
    }

    // ---- epilogue: bias (+relu); fp16 store ----
#pragma unroll
    for (int ni = 0; ni < 4; ni++) {
        int col = cb + wc + ni * 16 + r15;
        float bbias = bptr[e * bestride + col];
#pragma unroll
        for (int mi = 0; mi < 4; mi++) {
            int row0 = rb + wr + mi * 16 + lg * 4;
#pragma unroll
            for (int rr = 0; rr < 4; rr++) {
                float v = acc[mi][ni][rr] + bbias;
                if (RELU) v = fmaxf(v, 0.f);
                Ch[(size_t)(row0 + rr) * DD + col] = f16bits(v);
            }
        }
    }
}

// ---------------- combine: out[n] = w0*y[p0] + w1*y[p1] (y fp16) ----------------
__global__ void combine_kernel(int t0, int T,
                               const u16* __restrict__ y,
                               const int* __restrict__ posl,
                               const float* __restrict__ wts,
                               float* __restrict__ out) {
    int idx = blockIdx.x * blockDim.x + threadIdx.x;
    if (idx >= T * (DD / 4)) return;
    int i = idx >> 7;
    int j = idx & 127;
    int p0 = posl[2 * i], p1 = posl[2 * i + 1];
    float w0 = wts[2 * i], w1 = wts[2 * i + 1];
    ushort4 a = ((const ushort4*)(y + (size_t)p0 * DD))[j];
    ushort4 b = ((const ushort4*)(y + (size_t)p1 * DD))[j];
    float4 c;
    c.x = w0 * h2f(a.x) + w1 * h2f(b.x);
    c.y = w0 * h2f(a.y) + w1 * h2f(b.y);
    c.z = w0 * h2f(a.z) + w1 * h2f(b.z);
    c.w = w0 * h2f(a.w) + w1 * h2f(b.w);
    ((float4*)(out + (size_t)(t0 + i) * DD))[j] = c;
}

extern "C" void kernel_launch(void* const* d_in, const int* in_sizes, int n_in,
                              void* d_out, int out_size, void* d_ws, size_t ws_size,
                              hipStream_t stream) {
    const float* x  = (const float*)d_in[0];
    const float* Wg = (const float*)d_in[1];
    const float* bg = (const float*)d_in[2];
    const float* Wh = (const float*)d_in[3];
    const float* bh = (const float*)d_in[4];
    const float* Wo = (const float*)d_in[5];
    const float* bo = (const float*)d_in[6];
    float* out = (float*)d_out;

    const size_t WT_ELEMS = (size_t)NE * 4 * DD * DD;   // 8.39M fp16
    int T = NTOK;
    while (T > 64) {
        size_t C = 2 * (size_t)T + NE * BM;
        size_t need = 4096 + WT_ELEMS * 2 + 3 * ((size_t)T * 2 * 4)
                    + C * 4 + 512
                    + 3 * (C * (size_t)DD * 2);   // bufA, bufB, bufY fp16
        if (need <= ws_size) break;
        T >>= 1;
    }
    int phases = (NTOK + T - 1) / T;
    size_t C = 2 * (size_t)T + NE * BM;

    char* p = (char*)d_ws;
    int* counts = (int*)p;
    int* off    = (int*)(p + 64);
    int* cursor = (int*)(p + 128);
    char* q = p + 4096;
    u16* Wt = (u16*)q;    q += WT_ELEMS * 2;
    int* eids = (int*)q;  q += (size_t)T * 2 * 4;
    int* posl = (int*)q;  q += (size_t)T * 2 * 4;
    float* wts = (float*)q; q += (size_t)T * 2 * 4;
    int* list_token = (int*)q; q += C * 4;
    q = (char*)(((uintptr_t)q + 255) & ~(uintptr_t)255);
    u16* bufA = (u16*)q;  q += C * DD * 2;
    u16* bufB = (u16*)q;  q += C * DD * 2;
    u16* bufY = (u16*)q;

    convert_w<<<dim3(16, 16, 32), dim3(32, 8), 0, stream>>>(Wh, Wo, Wt);

    for (int ph = 0; ph < phases; ph++) {
        int t0 = ph * T;
        int Tc = (NTOK - t0 < T) ? (NTOK - t0) : T;

        hipMemsetAsync(counts, 0, 256, stream);
        hipMemsetAsync(list_token, 0xFF, C * 4, stream);

        route_kernel<<<(Tc + RBLK - 1) / RBLK, RBLK, 0, stream>>>(
            x, Wg, bg, t0, Tc, counts, eids, wts);
        offsets_kernel<<<1, 64, 0, stream>>>(counts, off, cursor);
        scatter_kernel<<<(Tc + RBLK - 1) / RBLK, RBLK, 0, stream>>>(
            t0, Tc, eids, cursor, list_token, posl);

        // grid: (C/BM) row-panels x 4 col-blocks, 1-D, multiple of 8 for XCD swizzle
        unsigned NB = (unsigned)(C / BM) * (DD / BN);
        moe_gemm<true, true><<<NB, 256, 0, stream>>>(
            x, nullptr, list_token, Wt, 0,
            bh, 3 * DD, off, bufA);
        moe_gemm<false, true><<<NB, 256, 0, stream>>>(
            nullptr, bufA, nullptr, Wt, 1,
            bh + DD, 3 * DD, off, bufB);
        moe_gemm<false, true><<<NB, 256, 0, stream>>>(
            nullptr, bufB, nullptr, Wt, 2,
            bh + 2 * DD, 3 * DD, off, bufA);
        moe_gemm<false, false><<<NB, 256, 0, stream>>>(
            nullptr, bufA, nullptr, Wt, 3,
            bo, DD, off, bufY);

        combine_kernel<<<((size_t)Tc * (DD / 4) + 255) / 256, 256, 0, stream>>>(
            t0, Tc, bufY, posl, wts, out);
    }
}